// Round 3
// baseline (620.596 us; speedup 1.0000x reference)
//
#include <hip/hip_runtime.h>
#include <math.h>

#define NPTS 65536
#define EPSV 1e-5f
#define B1G  256    // kernel-1 grid
#define B3G  1024   // kernel-3 grid (64 n per block)

// workspace float offsets (part1 and part2 share region: disjoint lifetimes)
#define OFF_PART 0                    // max(B1G*65, B3G*128) = 131072
#define OFF_S1   131072               // 256 : scale1[128], shift1[128]
#define OFF_S2   (OFF_S1+256)         // 128 : scale2[64], shift2[64]
#define OFF_PRE  (OFF_S2+128)         // NPTS*64

typedef unsigned int u32;
typedef short v8s __attribute__((ext_vector_type(8)));   // 8 bf16 = 4 VGPRs (MFMA A/B frag)
typedef float v4f __attribute__((ext_vector_type(4)));   // MFMA C/D frag

union F8 { v8s v; u32 u[4]; unsigned short s[8]; };

__device__ __forceinline__ u32 f2bf(float f){
  u32 u = __float_as_uint(f);
  return (u + 0x7fffu + ((u>>16)&1u)) >> 16;   // RNE to bf16
}
__device__ __forceinline__ float bf2f(unsigned short s){ return __uint_as_float(((u32)s)<<16); }
__device__ __forceinline__ u32 packbf(float a, float b){
#if __has_builtin(__builtin_amdgcn_cvt_pk_bf16_f32)
  auto rv = __builtin_amdgcn_cvt_pk_bf16_f32(a, b);     // 1 VALU op, RNE, lo=a hi=b
  u32 u; __builtin_memcpy(&u, &rv, 4);
  return u;
#else
  return f2bf(a) | (f2bf(b)<<16);
#endif
}

// ---------------- kernel 1: Gram-matrix stats over all N*K rows -------------
// Sum_h = (Sum c)@w1 ; Sum_h2 = w1^T (Sum c c^T) w1 (b1 cancels in BN).
__global__ __launch_bounds__(256) void k1_stats(const float* __restrict__ p, float* __restrict__ part1){
  int tid = blockIdx.x*256 + threadIdx.x;
  float M[55]; float s[10];
  #pragma unroll
  for(int i=0;i<55;i++) M[i]=0.f;
  #pragma unroll
  for(int i=0;i<10;i++) s[i]=0.f;
  for(int it=0; it<16; ++it){
    int r = it*65536 + tid;
    int n = r >> 4;
    int kk = r & 15;
    const float* pn = p + (size_t)n*48;
    float cx=pn[0], cy=pn[1], cz=pn[2];
    float ax=pn[kk*3+0], ay=pn[kk*3+1], az=pn[kk*3+2];
    float dx=cx-ax, dy=cy-ay, dz=cz-az;
    float dd = sqrtf(dx*dx+dy*dy+dz*dz);
    float c[10]={cx,cy,cz,ax,ay,az,dx,dy,dz,dd};
    #pragma unroll
    for(int i=0;i<10;i++) s[i]+=c[i];
    int idx=0;
    #pragma unroll
    for(int i=0;i<10;i++){
      #pragma unroll
      for(int j=i;j<10;j++){
        M[idx] = fmaf(c[i],c[j],M[idx]);
        idx++;
      }
    }
  }
  #pragma unroll
  for(int i=0;i<10;i++){
    for(int off=32; off>0; off>>=1) s[i] += __shfl_down(s[i], off, 64);
  }
  #pragma unroll
  for(int i=0;i<55;i++){
    for(int off=32; off>0; off>>=1) M[i] += __shfl_down(M[i], off, 64);
  }
  __shared__ float sm[4][65];
  int lane = threadIdx.x & 63, w = threadIdx.x >> 6;
  if(lane==0){
    #pragma unroll
    for(int i=0;i<10;i++) sm[w][i]=s[i];
    #pragma unroll
    for(int i=0;i<55;i++) sm[w][10+i]=M[i];
  }
  __syncthreads();
  if(threadIdx.x<65){
    float v = sm[0][threadIdx.x]+sm[1][threadIdx.x]+sm[2][threadIdx.x]+sm[3][threadIdx.x];
    part1[blockIdx.x*65 + threadIdx.x] = v;
  }
}

// ---------------- kernel 2: finalize BN1 scale/shift ------------------------
__device__ __forceinline__ int tri_idx(int i,int j){
  int a = i<j? i : j;
  int b = i<j? j : i;
  return 10*a - (a*(a-1))/2 + (b-a);
}
__global__ void k2_fin(const float* __restrict__ part1, const float* __restrict__ w1,
                       const float* __restrict__ g1, const float* __restrict__ be1,
                       float* __restrict__ stats1){
  __shared__ float S[65];
  int t = threadIdx.x; // 128 threads
  if(t<65){
    float a=0.f;
    for(int b=0;b<B1G;b++) a += part1[b*65+t];
    S[t]=a;
  }
  __syncthreads();
  float wc[10];
  #pragma unroll
  for(int c=0;c<10;c++) wc[c]=w1[c*128+t];
  float md=0.f;
  #pragma unroll
  for(int c=0;c<10;c++) md += S[c]*wc[c];
  const float invR = 1.0f/(float)(NPTS*16);
  md *= invR;
  float q=0.f;
  #pragma unroll
  for(int i=0;i<10;i++){
    float ti=0.f;
    #pragma unroll
    for(int j=0;j<10;j++) ti += S[10+tri_idx(i,j)]*wc[j];
    q = fmaf(ti, wc[i], q);
  }
  q *= invR;
  float var = q - md*md;
  float sc = g1[t]*rsqrtf(var+EPSV);
  float sh = be1[t] - md*sc;            // b1 cancels inside BN
  stats1[t]=sc;
  stats1[128+t]=sh;
}

// ---------------- kernel 3: MFMA block-cooperative pipeline -----------------
// 4 waves/block, 2 n per round, 32 rounds (64 n per block), 4 blocks/CU.
// Wave w owns channel slice: 32 ch of {h, logits}, 16 ch of {p_c, out}.
// All weights live in VGPRs as 16x16x32 bf16 B-fragments, loaded ONCE.
// h-LDS uses interleaved channel positions: pos(32a+c)=32a+2c, pos(32a+16+c)=32a+2c+1
// so each lane's two MFMA outputs pack into one b32 store; w2's B-fragment rows
// are gathered with the same permutation (k-reduction is order-invariant).
// Logits LDS uses the same pairing for b64 stores; stage4 decodes position.
// lane = 16q + c.
__global__ __launch_bounds__(256,4) void k3_main(
    const float* __restrict__ p, const float* __restrict__ x,
    const float* __restrict__ w2, const float* __restrict__ b2,
    const float* __restrict__ wsm, const float* __restrict__ wo,
    const float* __restrict__ w1, const float* __restrict__ stats1,
    float* __restrict__ pre, float* __restrict__ part2)
{
  __shared__ __align__(16) unsigned short s_h [2][16][136];  // h bf16, interleaved pos
  __shared__ __align__(16) unsigned short s_px[2][16][136];  // p_x bf16: pos=ch identity
  __shared__ __align__(16) float          s_lg[2][16][132];  // logits fp32, interleaved pos
  __shared__ __align__(16) unsigned short s_ft[16][136];     // feat bf16 (16-n batch)

  const int tid  = threadIdx.x;
  const int w    = tid>>6;
  const int lane = tid&63;
  const int q    = lane>>4;
  const int c    = lane&15;

  // ---- register-resident B fragments (k = kk*32 + q*8 + j) ----------------
  v8s Bw1[2], Bw2[4], Bws[2][4], Bwo[4];
  #pragma unroll
  for(int t=0;t<2;t++){
    F8 f;
    #pragma unroll
    for(int j=0;j<8;j++){
      int k = q*8+j;
      f.s[j] = (unsigned short)(k<10 ? f2bf(w1[k*128 + 32*w + 16*t + c]) : 0);
    }
    Bw1[t]=f.v;
  }
  #pragma unroll
  for(int kk=0;kk<4;kk++){
    F8 f;
    #pragma unroll
    for(int j=0;j<8;j++){
      int pos = kk*32 + q*8 + j;                         // position in s_h
      int ch  = 32*(pos>>5) + 16*(pos&1) + ((pos>>1)&15); // interleave decode
      f.s[j]=(unsigned short)f2bf(w2[ch*64 + 16*w + c]);
    }
    Bw2[kk]=f.v;
  }
  #pragma unroll
  for(int t=0;t<2;t++){
    #pragma unroll
    for(int kk=0;kk<4;kk++){
      F8 f;
      #pragma unroll
      for(int j=0;j<8;j++) f.s[j]=(unsigned short)f2bf(wsm[(kk*32+q*8+j)*128 + 32*w + 16*t + c]);
      Bws[t][kk]=f.v;
    }
  }
  #pragma unroll
  for(int kk=0;kk<4;kk++){
    F8 f;
    #pragma unroll
    for(int j=0;j<8;j++) f.s[j]=(unsigned short)f2bf(wo[(kk*32+q*8+j)*64 + 16*w + c]);
    Bwo[kk]=f.v;
  }
  const float sc1a = stats1[32*w+c],    sh1a = stats1[128+32*w+c];
  const float sc1b = stats1[32*w+16+c], sh1b = stats1[128+32*w+16+c];
  const float b2v  = b2[16*w+c];

  // stage4 ownership: waves 0,1 -> n0=0 ; waves 2,3 -> n0=1 ; half by w&1
  const int n0s4 = w>>1;
  const int ch4  = 64*(w&1) + lane;                       // p_x channel (identity pos)
  const int lpos = 32*(ch4>>5) + 2*(ch4&15) + ((ch4>>4)&1); // logit LDS position

  float a_s=0.f, a_q=0.f;
  const int base0 = blockIdx.x*64;

  for(int r=0;r<32;++r){
    const int base = base0 + 2*r;

    // ---- x rows -> s_px[ch 64..127] bf16 (coalesced float4 loads) ---------
    const float4* xg = (const float4*)(x + (size_t)base*1024);
    #pragma unroll
    for(int rr=0;rr<2;rr++){
      int f = tid + 256*rr;                // 512 float4 per round (2 n)
      float4 v = xg[f];
      int n0 = f>>8, rem = f&255, pt = rem>>4, d4 = rem&15;
      *(uint2*)&s_px[n0][pt][64+4*d4] = make_uint2(packbf(v.x,v.y), packbf(v.z,v.w));
    }

    // ---- stage1: h = concat@w1 -> BN1 -> relu -> s_h (interleaved b32) ----
    #pragma unroll
    for(int n0=0;n0<2;n0++){
      F8 fa;
      fa.u[0]=0u; fa.u[1]=0u; fa.u[2]=0u; fa.u[3]=0u;
      if(q<2){                             // k>=16 lanes carry zeros (concat dim=10)
        const float* pn = p + (size_t)(base+n0)*48;
        float cx=pn[0], cy=pn[1], cz=pn[2];
        float ax=pn[3*c], ay=pn[3*c+1], az=pn[3*c+2];   // lane's point m=c
        float dx=cx-ax, dy=cy-ay, dz=cz-az;
        float dd=sqrtf(dx*dx+dy*dy+dz*dz);
        if(q==0){
          fa.u[0]=packbf(cx,cy); fa.u[1]=packbf(cz,ax);
          fa.u[2]=packbf(ay,az); fa.u[3]=packbf(dx,dy);
        }else{
          fa.u[0]=packbf(dz,dd);
        }
      }
      v4f z={0.f,0.f,0.f,0.f};
      v4f d0 = __builtin_amdgcn_mfma_f32_16x16x32_bf16(fa.v, Bw1[0], z, 0,0,0);
      v4f d1 = __builtin_amdgcn_mfma_f32_16x16x32_bf16(fa.v, Bw1[1], z, 0,0,0);
      #pragma unroll
      for(int i=0;i<4;i++){
        float v0 = fmaxf(0.f, fmaf(d0[i], sc1a, sh1a));
        float v1 = fmaxf(0.f, fmaf(d1[i], sc1b, sh1b));
        *(u32*)&s_h[n0][4*q+i][32*w+2*c] = packbf(v0,v1);
      }
    }
    __syncthreads();

    // ---- stage2: p_c = h@w2 + b2 -> s_px[ch 0..63] bf16 -------------------
    #pragma unroll
    for(int n0=0;n0<2;n0++){
      const v8s* Ar = (const v8s*)&s_h[n0][c][0];
      v4f acc={0.f,0.f,0.f,0.f};
      #pragma unroll
      for(int kk=0;kk<4;kk++)
        acc = __builtin_amdgcn_mfma_f32_16x16x32_bf16(Ar[kk*4+q], Bw2[kk], acc, 0,0,0);
      u32 pa = packbf(acc[0]+b2v, acc[1]+b2v);
      u32 pb = packbf(acc[2]+b2v, acc[3]+b2v);
      s_px[n0][4*q+0][16*w+c] = (unsigned short)pa;
      s_px[n0][4*q+1][16*w+c] = (unsigned short)(pa>>16);
      s_px[n0][4*q+2][16*w+c] = (unsigned short)pb;
      s_px[n0][4*q+3][16*w+c] = (unsigned short)(pb>>16);
    }
    __syncthreads();

    // ---- stage3: logits = p_x@ws -> s_lg fp32 (interleaved, b64 stores) ---
    #pragma unroll
    for(int n0=0;n0<2;n0++){
      const v8s* Ar = (const v8s*)&s_px[n0][c][0];
      v4f l0={0.f,0.f,0.f,0.f}, l1={0.f,0.f,0.f,0.f};
      #pragma unroll
      for(int kk=0;kk<4;kk++){
        v8s a = Ar[kk*4+q];
        l0 = __builtin_amdgcn_mfma_f32_16x16x32_bf16(a, Bws[0][kk], l0, 0,0,0);
        l1 = __builtin_amdgcn_mfma_f32_16x16x32_bf16(a, Bws[1][kk], l1, 0,0,0);
      }
      #pragma unroll
      for(int i=0;i<4;i++)
        *(float2*)&s_lg[n0][4*q+i][32*w+2*c] = make_float2(l0[i], l1[i]);
    }
    __syncthreads();

    // ---- stage4: softmax over points + attention pool (no max-sub:
    //      logits ~ N(0,1), fp32 exp safe) ----------------------------------
    {
      float se=0.f, fe=0.f;
      #pragma unroll
      for(int pt=0;pt<16;pt++){
        float e = __expf(s_lg[n0s4][pt][lpos]);
        se += e;
        fe = fmaf(e, bf2f(s_px[n0s4][pt][ch4]), fe);
      }
      s_ft[(r&7)*2+n0s4][ch4] = (unsigned short)f2bf(__fdividef(fe,se));
    }
    __syncthreads();   // protects s_ft before stage5 AND s_px/s_lg/s_h reuse

    // ---- stage5: out = feat@wo for 16 buffered n (every 8 rounds) ---------
    if((r&7)==7){
      const v8s* Ar = (const v8s*)&s_ft[c][0];
      v4f o={0.f,0.f,0.f,0.f};
      #pragma unroll
      for(int kk=0;kk<4;kk++)
        o = __builtin_amdgcn_mfma_f32_16x16x32_bf16(Ar[kk*4+q], Bwo[kk], o, 0,0,0);
      const int nb16 = base0 + (r>>3)*16;
      #pragma unroll
      for(int i=0;i<4;i++){
        float val = o[i];
        pre[(size_t)(nb16 + 4*q + i)*64 + 16*w + c] = val;
        a_s += val;
        a_q = fmaf(val,val,a_q);
      }
    }
  }

  // ---- BN2 partials: reduce over quads (same d = 16w+c across q) ----------
  a_s += __shfl_xor(a_s, 16, 64); a_s += __shfl_xor(a_s, 32, 64);
  a_q += __shfl_xor(a_q, 16, 64); a_q += __shfl_xor(a_q, 32, 64);
  if(q==0){
    part2[blockIdx.x*128 + 16*w + c]      = a_s;
    part2[blockIdx.x*128 + 64 + 16*w + c] = a_q;
  }
}

// ---------------- kernel 4: finalize BN2 scale/shift ------------------------
__global__ void k4_fin(const float* __restrict__ part2, const float* __restrict__ g2,
                       const float* __restrict__ be2, float* __restrict__ stats2){
  __shared__ float red[256];
  int t = threadIdx.x;                 // 256 threads
  int j = t & 127, g = t >> 7;
  float s = 0.f;
  for(int b=g;b<B3G;b+=2) s += part2[b*128 + j];
  red[t] = s;
  __syncthreads();
  if(t<64){
    float su = red[t]    + red[128+t];
    float qq = red[64+t] + red[192+t];
    float mu  = su/(float)NPTS;
    float var = qq/(float)NPTS - mu*mu;
    float sc = g2[t]*rsqrtf(var+EPSV);
    stats2[t]=sc;
    stats2[64+t]=be2[t]-mu*sc;         // bo cancels inside BN
  }
}

// ---------------- kernel 5: apply BN2 + relu --------------------------------
__global__ __launch_bounds__(256) void k5_apply(const float* __restrict__ pre,
                                                const float* __restrict__ stats2,
                                                float* __restrict__ out){
  int i = blockIdx.x*256 + threadIdx.x;      // float4 index; 1,048,576 total
  float4 v = ((const float4*)pre)[i];
  int d4 = i & 15;
  float4 sc = ((const float4*)stats2)[d4];
  float4 sh = ((const float4*)(stats2+64))[d4];
  float4 o;
  o.x = fmaxf(0.f, fmaf(v.x,sc.x,sh.x));
  o.y = fmaxf(0.f, fmaf(v.y,sc.y,sh.y));
  o.z = fmaxf(0.f, fmaf(v.z,sc.z,sh.z));
  o.w = fmaxf(0.f, fmaf(v.w,sc.w,sh.w));
  ((float4*)out)[i] = o;
}

extern "C" void kernel_launch(void* const* d_in, const int* in_sizes, int n_in,
                              void* d_out, int out_size, void* d_ws, size_t ws_size,
                              hipStream_t stream){
  (void)in_sizes; (void)n_in; (void)out_size; (void)ws_size;
  const float* p   = (const float*)d_in[0];
  const float* x   = (const float*)d_in[1];
  const float* w1  = (const float*)d_in[2];
  // d_in[3] = b1  : cancels inside BN1
  const float* g1  = (const float*)d_in[4];
  const float* be1 = (const float*)d_in[5];
  const float* w2  = (const float*)d_in[6];
  const float* b2  = (const float*)d_in[7];
  const float* wsm = (const float*)d_in[8];
  const float* wo  = (const float*)d_in[9];
  // d_in[10] = bo : cancels inside BN2
  const float* g2  = (const float*)d_in[11];
  const float* be2 = (const float*)d_in[12];

  float* wsf    = (float*)d_ws;
  float* part1  = wsf + OFF_PART;     // k1->k2, dead after k2
  float* part2  = wsf + OFF_PART;     // k3->k4 (same region, disjoint lifetime)
  float* stats1 = wsf + OFF_S1;
  float* stats2 = wsf + OFF_S2;
  float* pre    = wsf + OFF_PRE;
  float* out    = (float*)d_out;

  k1_stats<<<B1G,256,0,stream>>>(p, part1);
  k2_fin  <<<1,128,0,stream>>>(part1, w1, g1, be1, stats1);
  k3_main <<<B3G,256,0,stream>>>(p,x,w2,b2,wsm,wo,w1,stats1,pre,part2);
  k4_fin  <<<1,256,0,stream>>>(part2,g2,be2,stats2);
  k5_apply<<<4096,256,0,stream>>>(pre,stats2,out);
}